// Round 6
// baseline (823.040 us; speedup 1.0000x reference)
//
#include <hip/hip_runtime.h>

#define Nn 4096
#define Cc 256
#define NN2 ((size_t)Nn * Nn)

typedef __attribute__((ext_vector_type(8))) short bf16x8;
typedef __attribute__((ext_vector_type(4))) float f32x4;

__device__ __forceinline__ unsigned short f2bf(float f) {
    union { float f; unsigned u; } v; v.f = f;
    unsigned r = v.u + 0x7FFF + ((v.u >> 16) & 1);
    return (unsigned short)(r >> 16);
}

__device__ __forceinline__ bf16x8 pack2(const float4& a, const float4& b) {
    bf16x8 o;
    o[0] = (short)f2bf(a.x); o[1] = (short)f2bf(a.y);
    o[2] = (short)f2bf(a.z); o[3] = (short)f2bf(a.w);
    o[4] = (short)f2bf(b.x); o[5] = (short)f2bf(b.y);
    o[6] = (short)f2bf(b.z); o[7] = (short)f2bf(b.w);
    return o;
}

// exp 8 floats (two float4), accumulate sum into sacc, return packed bf16x8
__device__ __forceinline__ bf16x8 exp8acc(const float4 a, const float4 b, float& sacc) {
    const float s0 = __expf(a.x), s1 = __expf(a.y), s2 = __expf(a.z), s3 = __expf(a.w);
    const float s4 = __expf(b.x), s5 = __expf(b.y), s6 = __expf(b.z), s7 = __expf(b.w);
    sacc += ((s0 + s1) + (s2 + s3)) + ((s4 + s5) + (s6 + s7));
    bf16x8 o;
    o[0] = (short)f2bf(s0); o[1] = (short)f2bf(s1);
    o[2] = (short)f2bf(s2); o[3] = (short)f2bf(s3);
    o[4] = (short)f2bf(s4); o[5] = (short)f2bf(s5);
    o[6] = (short)f2bf(s6); o[7] = (short)f2bf(s7);
    return o;
}

// ---------------------------------------------------------------------------
// Kernel 1: V[b,o,n] = bf16( sum_c W[o,c]*X[b,c,n] + bias[o] )  (unchanged)
// ---------------------------------------------------------------------------
__global__ __launch_bounds__(256) void value_gemm(
    const float* __restrict__ X, const float* __restrict__ W,
    const float* __restrict__ bias, unsigned short* __restrict__ Vout)
{
    __shared__ float Xs[256][33];

    const int t = threadIdx.x;
    const int b  = blockIdx.x >> 7;
    const int n0 = (blockIdx.x & 127) << 5;
    const int wave = t >> 6, lane = t & 63;
    const int lrow = lane & 15, lq = lane >> 4;

    const float* Xb = X + (size_t)b * Cc * Nn + n0;

    {
        const int r0 = t >> 3, c4 = (t & 7) << 2;
        #pragma unroll
        for (int i = 0; i < 8; ++i) {
            const int r = r0 + i * 32;
            const float4 v = *(const float4*)(Xb + (size_t)r * Nn + c4);
            Xs[r][c4 + 0] = v.x; Xs[r][c4 + 1] = v.y;
            Xs[r][c4 + 2] = v.z; Xs[r][c4 + 3] = v.w;
        }
    }
    __syncthreads();

    f32x4 acc[4][2] = {};

    #pragma unroll 2
    for (int k0 = 0; k0 < Cc; k0 += 32) {
        bf16x8 af[4];
        #pragma unroll
        for (int ci = 0; ci < 4; ++ci) {
            const float* wp = W + (size_t)(wave * 64 + ci * 16 + lrow) * Cc + k0 + lq * 8;
            af[ci] = pack2(*(const float4*)wp, *(const float4*)(wp + 4));
        }
        bf16x8 bp[2];
        #pragma unroll
        for (int mi = 0; mi < 2; ++mi) {
            const int n = mi * 16 + lrow;
            bf16x8 o;
            #pragma unroll
            for (int j = 0; j < 8; ++j) o[j] = (short)f2bf(Xs[k0 + lq * 8 + j][n]);
            bp[mi] = o;
        }
        #pragma unroll
        for (int ci = 0; ci < 4; ++ci)
            #pragma unroll
            for (int mi = 0; mi < 2; ++mi)
                acc[ci][mi] = __builtin_amdgcn_mfma_f32_16x16x32_bf16(
                    af[ci], bp[mi], acc[ci][mi], 0, 0, 0);
    }

    #pragma unroll
    for (int ci = 0; ci < 4; ++ci) {
        #pragma unroll
        for (int rr = 0; rr < 4; ++rr) {
            const int o = wave * 64 + ci * 16 + lq * 4 + rr;
            const float bo = bias[o];
            #pragma unroll
            for (int mi = 0; mi < 2; ++mi) {
                const int n = n0 + mi * 16 + lrow;
                Vout[((size_t)(b * Cc + o)) * Nn + n] = f2bf(acc[ci][mi][rr] + bo);
            }
        }
    }
}

// ---------------------------------------------------------------------------
// Kernel 2 v6: BARRIER-FREE, LDS-FREE, spill-free this time.
// Round 3's idea with the round-3 bug fixed: __launch_bounds__(512, 2) gives
// a 256-VGPR cap so the ~190-reg ping-pong working set does NOT spill and
// prefetch loads survive regalloc (r3 failure signature: VGPR=128 + 106 MB
// scratch writes; check WRITE_SIZE stays ~16 MB).
// Block 512 = 8 free-running waves = 4 c-slices(64) x 2 m-halves(32) of one
// (b, 64-row m-tile). E shared across c-slice waves via L1/L2 (exp computed
// x4 redundantly — the price of decoupling). Grid 256 = 4b x 64 mtiles,
// 1 block/CU; b=blk&3 pins batch V to XCDs {b,b+4}.
// Each wave: own E/V register ping-pong at distance 2, zero syncthreads,
// zero LDS; softmax denom from lane-local sums via shfl_xor over lq groups.
// ---------------------------------------------------------------------------
__global__ __launch_bounds__(512, 2) void attn_gemm(
    const unsigned short* __restrict__ V, const float* __restrict__ E,
    const float* __restrict__ X, const float* __restrict__ gamma,
    float* __restrict__ Out)
{
    const int t = threadIdx.x;
    const int wave = t >> 6, lane = t & 63;
    const int lrow = lane & 15, lq = lane >> 4;
    const int blk = blockIdx.x;
    const int b  = blk & 3;
    const int m0 = (blk >> 2) << 6;     // 64-row m-tile
    const int c0 = (wave & 3) << 6;     // c-slice
    const int mh = (wave >> 2) << 5;    // m-half (0 or 32)

    // E row pointers for this lane's two m-rows (mi=0: mh+lrow, mi=1: mh+16+lrow)
    const float* ep0 = E + (size_t)b * NN2 + (size_t)(m0 + mh + lrow) * Nn + lq * 8;
    const float* ep1 = ep0 + (size_t)16 * Nn;

    // V fragments: rows c0+ci*16+lrow, cols lq*8 (+ k*64 + kk*32)
    const unsigned short* vbase = V + (size_t)(b * Cc + c0) * Nn;
    int voff[4];
    #pragma unroll
    for (int ci = 0; ci < 4; ++ci) voff[ci] = (ci * 16 + lrow) * Nn + lq * 8;

    f32x4 acc[4][2] = {};            // [ci][mi]
    float sacc0 = 0.f, sacc1 = 0.f;  // exp sums for rows mh+lrow / mh+16+lrow

    // E regs: [mi*4 + kk*2 + h]; V regs: [kk*4 + ci]. Ping-pong A/B.
    float4 eA[8], eB[8];
    bf16x8 vA[8], vB[8];

    // ---- prologue: k=0 -> A, k=1 -> B ----
    #pragma unroll
    for (int kk = 0; kk < 2; ++kk) {
        eA[0 + kk * 2 + 0] = *(const float4*)(ep0 + kk * 32);
        eA[0 + kk * 2 + 1] = *(const float4*)(ep0 + kk * 32 + 4);
        eA[4 + kk * 2 + 0] = *(const float4*)(ep1 + kk * 32);
        eA[4 + kk * 2 + 1] = *(const float4*)(ep1 + kk * 32 + 4);
        eB[0 + kk * 2 + 0] = *(const float4*)(ep0 + 64 + kk * 32);
        eB[0 + kk * 2 + 1] = *(const float4*)(ep0 + 64 + kk * 32 + 4);
        eB[4 + kk * 2 + 0] = *(const float4*)(ep1 + 64 + kk * 32);
        eB[4 + kk * 2 + 1] = *(const float4*)(ep1 + 64 + kk * 32 + 4);
    }
    #pragma unroll
    for (int kk = 0; kk < 2; ++kk)
        #pragma unroll
        for (int ci = 0; ci < 4; ++ci) {
            vA[kk * 4 + ci] = *(const bf16x8*)(vbase + voff[ci] + kk * 32);
            vB[kk * 4 + ci] = *(const bf16x8*)(vbase + voff[ci] + 64 + kk * 32);
        }

    // half-step: consume E/V set for step ks, refill same set for ks+2.
    // Order: exp(E) -> E prefetch issue -> MFMA -> V prefetch issue.
#define HALF(Ee, Vv, ks)                                                      \
    {                                                                          \
        bf16x8 bfr00 = exp8acc(Ee[0], Ee[1], sacc0);  /* mi0 kk0 */            \
        bf16x8 bfr01 = exp8acc(Ee[2], Ee[3], sacc0);  /* mi0 kk1 */            \
        bf16x8 bfr10 = exp8acc(Ee[4], Ee[5], sacc1);  /* mi1 kk0 */            \
        bf16x8 bfr11 = exp8acc(Ee[6], Ee[7], sacc1);  /* mi1 kk1 */            \
        const int kc = (((ks) + 2) & 63) << 6;                                 \
        Ee[0] = *(const float4*)(ep0 + kc);                                    \
        Ee[1] = *(const float4*)(ep0 + kc + 4);                                \
        Ee[2] = *(const float4*)(ep0 + kc + 32);                               \
        Ee[3] = *(const float4*)(ep0 + kc + 36);                               \
        Ee[4] = *(const float4*)(ep1 + kc);                                    \
        Ee[5] = *(const float4*)(ep1 + kc + 4);                                \
        Ee[6] = *(const float4*)(ep1 + kc + 32);                               \
        Ee[7] = *(const float4*)(ep1 + kc + 36);                               \
        _Pragma("unroll")                                                      \
        for (int ci = 0; ci < 4; ++ci) {                                       \
            acc[ci][0] = __builtin_amdgcn_mfma_f32_16x16x32_bf16(              \
                Vv[ci], bfr00, acc[ci][0], 0, 0, 0);                           \
            acc[ci][1] = __builtin_amdgcn_mfma_f32_16x16x32_bf16(              \
                Vv[ci], bfr10, acc[ci][1], 0, 0, 0);                           \
        }                                                                      \
        _Pragma("unroll")                                                      \
        for (int ci = 0; ci < 4; ++ci) {                                       \
            acc[ci][0] = __builtin_amdgcn_mfma_f32_16x16x32_bf16(              \
                Vv[4 + ci], bfr01, acc[ci][0], 0, 0, 0);                       \
            acc[ci][1] = __builtin_amdgcn_mfma_f32_16x16x32_bf16(              \
                Vv[4 + ci], bfr11, acc[ci][1], 0, 0, 0);                       \
        }                                                                      \
        _Pragma("unroll")                                                      \
        for (int ci = 0; ci < 4; ++ci) {                                       \
            Vv[ci]     = *(const bf16x8*)(vbase + voff[ci] + kc);              \
            Vv[4 + ci] = *(const bf16x8*)(vbase + voff[ci] + kc + 32);         \
        }                                                                      \
    }

    #pragma unroll 1
    for (int k = 0; k < 64; k += 2) {
        HALF(eA, vA, k);
        HALF(eB, vB, k + 1);
    }
#undef HALF

    // ---- softmax denominators: reduce lane sums over the 4 lq groups ----
    float s0 = sacc0;
    s0 += __shfl_xor(s0, 16);
    s0 += __shfl_xor(s0, 32);
    float s1 = sacc1;
    s1 += __shfl_xor(s1, 16);
    s1 += __shfl_xor(s1, 32);

    // ---- epilogue ----
    const float g = gamma[0];
    const float scale0 = g / s0, scale1 = g / s1;
    #pragma unroll
    for (int mi = 0; mi < 2; ++mi) {
        const int m = m0 + mh + mi * 16 + lrow;
        const float sc = mi ? scale1 : scale0;
        #pragma unroll
        for (int ci = 0; ci < 4; ++ci) {
            #pragma unroll
            for (int rr = 0; rr < 4; ++rr) {
                const int c = c0 + ci * 16 + lq * 4 + rr;
                const size_t off = ((size_t)(b * Cc + c)) * Nn + m;
                Out[off] = sc * acc[ci][mi][rr] + 2.0f * X[off];
            }
        }
    }
}

extern "C" void kernel_launch(void* const* d_in, const int* in_sizes, int n_in,
                              void* d_out, int out_size, void* d_ws, size_t ws_size,
                              hipStream_t stream) {
    const float* energy  = (const float*)d_in[0];  // [4,4096,4096]
    const float* x       = (const float*)d_in[1];  // [4,256,64,64]
    const float* value_w = (const float*)d_in[2];  // [256,256]
    const float* value_b = (const float*)d_in[3];  // [256]
    const float* gamma   = (const float*)d_in[4];  // [1]
    float* out = (float*)d_out;
    unsigned short* Vws = (unsigned short*)d_ws;   // 4*256*4096 bf16 = 8 MB

    value_gemm<<<512, 256, 0, stream>>>(x, value_w, value_b, Vws);
    attn_gemm<<<256, 512, 0, stream>>>(Vws, energy, x, gamma, out);
}